// Round 3
// baseline (980.010 us; speedup 1.0000x reference)
//
#include <hip/hip_runtime.h>
#include <cstdint>

// B=16, C=64, H=W=256. Three 3x3 convs via bf16 MFMA implicit GEMM.
// Round 3: depthwise+gate fused into conv3 epilogue (k_dw eliminated).
using short8  = __attribute__((ext_vector_type(8))) short;
using short4v = __attribute__((ext_vector_type(4))) short;
using f32x16  = __attribute__((ext_vector_type(16))) float;
using float4v = __attribute__((ext_vector_type(4))) float;
typedef unsigned short ushort_t;

__device__ __forceinline__ float lrelu(float x) { return x > 0.f ? x : 0.1f * x; }

__device__ __forceinline__ ushort_t f2bf(float f) {
    union { float f; unsigned u; } v; v.f = f;
    unsigned r = (v.u + 0x7FFFu + ((v.u >> 16) & 1u)) >> 16;
    return (ushort_t)r;
}
__device__ __forceinline__ float bf2f(ushort_t b) {
    union { unsigned u; float f; } v; v.u = ((unsigned)b) << 16; return v.f;
}

// ---------------------------------------------------------------------------
// Tiny branch: mv[b][c]; kern transposed to ktr[b][tap][c] for float4 loads.
// ---------------------------------------------------------------------------
__global__ void k_tiny(const float* __restrict__ t, const float* __restrict__ tW1,
                       const float* __restrict__ tW2, const float* __restrict__ kW1,
                       const float* __restrict__ kW2, float* __restrict__ mv,
                       float* __restrict__ ktr) {
    int b = blockIdx.x;
    int c = threadIdx.x;  // 64
    __shared__ float h1[64], g1[64];
    float ts = t[b];
    h1[c] = lrelu(ts * tW1[c]);
    g1[c] = lrelu(ts * kW1[c]);
    __syncthreads();
    float s = 0.f;
    for (int j = 0; j < 64; ++j) s = fmaf(tW2[c * 64 + j], h1[j], s);
    mv[b * 64 + c] = 1.f / (1.f + expf(-s));
    for (int q = 0; q < 9; ++q) {
        float s2 = 0.f;
        for (int j = 0; j < 64; ++j) s2 = fmaf(kW2[(c * 9 + q) * 64 + j], g1[j], s2);
        ktr[b * 576 + q * 64 + c] = lrelu(s2);
    }
}

// ---------------------------------------------------------------------------
// Pack three 64x64x3x3 weight tensors into MFMA A-fragment order (bf16).
// Frag layout: flat = (((t*2+ch)*2+kc)*2+ct)*512 + lane*8 + j
//   element  = W[co = ct*32 + (lane&31)][ci = ch*32 + kc*16 + (lane>>5)*8 + j], tap t
// ---------------------------------------------------------------------------
__global__ void k_pack(const float* __restrict__ w1, const float* __restrict__ w2,
                       const float* __restrict__ w3, ushort_t* __restrict__ wp) {
    int idx = blockIdx.x * 256 + threadIdx.x;
    if (idx >= 3 * 36864) return;
    int conv = idx / 36864, r = idx % 36864;
    const float* W = conv == 0 ? w1 : (conv == 1 ? w2 : w3);
    int j = r & 7, lane = (r >> 3) & 63, ct = (r >> 9) & 1, kc = (r >> 10) & 1,
        ch = (r >> 11) & 1, t = r >> 12;
    int co = ct * 32 + (lane & 31);
    int ci = ch * 32 + kc * 16 + (lane >> 5) * 8 + j;
    wp[idx] = f2bf(W[(co * 64 + ci) * 9 + t]);
}

// ---------------------------------------------------------------------------
// Transpose x: fp32 NCHW -> bf16 NHWC. Block = (b,h).
// ---------------------------------------------------------------------------
__global__ __launch_bounds__(256) void k_tr(const float* __restrict__ x,
                                            ushort_t* __restrict__ xbf) {
    int bid = blockIdx.x;
    int h = bid & 255, b = bid >> 8;
    int t = threadIdx.x;
    for (int it = 0; it < 8; ++it) {
        int idx = t + it * 256;          // 0..2047 : (w, g)
        int g = idx & 7, w = idx >> 3;
        const float* src = x + (((size_t)(b * 64 + g * 8) * 256 + h) * 256 + w);
        short8 v;
#pragma unroll
        for (int j = 0; j < 8; ++j) v[j] = (short)f2bf(src[(size_t)j * 65536]);
        *(short8*)(xbf + (((size_t)(b * 256 + h) * 256 + w) * 64 + g * 8)) = v;
    }
}

// ---------------------------------------------------------------------------
// 3x3 conv 64->64 via v_mfma_f32_32x32x16_bf16.
// Block = (b, h): 4 waves, each computes 64 c_out x 64 pixels.
// LDS: [3 rows][130 pixel-pairs][8 swizzled 16B slots] = 48.75 KB.
// DW=true: fused final pass — epilogue stages f2 rows into the same LDS,
// computes 9-tap dynamic depthwise + mv gate, writes fp32 NCHW d_out.
// ---------------------------------------------------------------------------
template <bool LEAKY, bool DW>
__global__ __launch_bounds__(256, 3) void k_conv(const ushort_t* __restrict__ in,
                                                 const ushort_t* __restrict__ wp,
                                                 const float* __restrict__ bias,
                                                 const ushort_t* __restrict__ f2,
                                                 const float* __restrict__ ktr,
                                                 const float* __restrict__ mv,
                                                 void* __restrict__ outp) {
    __shared__ __align__(16) short xs[3 * 130 * 64];  // 49920 B
    const int tid = threadIdx.x;
    const int lane = tid & 63;
    const int wv = tid >> 6;
    const int bid = blockIdx.x;
    const int h = bid & 255, b = bid >> 8;
    const int l31 = lane & 31, lhi = lane >> 5;
    const int pw0 = wv * 64;

    f32x16 acc[2][2];
#pragma unroll
    for (int a = 0; a < 2; ++a)
#pragma unroll
        for (int c = 0; c < 2; ++c) acc[a][c] = (f32x16)0.0f;

    for (int ch = 0; ch < 2; ++ch) {
        __syncthreads();
        // stage 3 rows x 258 pixels x 32 ci (bf16) with XOR-swizzled slots
        for (int i = tid; i < 3 * 260 * 4; i += 256) {
            int g = i & 3;
            int p = (i >> 2) % 260;
            int r = (i >> 2) / 260;
            if (p >= 258) continue;
            int hs = h + r - 1, ws = p - 1;
            short8 v = (short8)0;
            if ((unsigned)hs < 256u && (unsigned)ws < 256u)
                v = *(const short8*)(in + (((size_t)(b * 256 + hs) * 256 + ws) * 64 +
                                           ch * 32 + g * 8));
            int slot = ((p & 1) * 4 + g) ^ ((p >> 1) & 7);
            *(short8*)(xs + ((r * 130 + (p >> 1)) * 8 + slot) * 8) = v;
        }
        __syncthreads();

#pragma unroll
        for (int t = 0; t < 9; ++t) {
            const int r = t / 3, dw = t % 3;
#pragma unroll
            for (int kc = 0; kc < 2; ++kc) {
                const ushort_t* wpf = wp + (((((t * 2 + ch) * 2 + kc) * 2) * 64 + lane) * 8);
                short8 a0 = *(const short8*)(wpf);
                short8 a1 = *(const short8*)(wpf + 512);
                const int g = kc * 2 + lhi;
#pragma unroll
                for (int pt = 0; pt < 2; ++pt) {
                    int p = pw0 + pt * 32 + l31 + dw;
                    int slot = ((p & 1) * 4 + g) ^ ((p >> 1) & 7);
                    short8 bf = *(const short8*)(xs + ((r * 130 + (p >> 1)) * 8 + slot) * 8);
                    acc[0][pt] = __builtin_amdgcn_mfma_f32_32x32x16_bf16(a0, bf, acc[0][pt], 0, 0, 0);
                    acc[1][pt] = __builtin_amdgcn_mfma_f32_32x32x16_bf16(a1, bf, acc[1][pt], 0, 0, 0);
                }
            }
        }
    }

    // Epilogue. D layout: col(pix)=lane&31, row(co)=(reg&3)+8*(reg>>2)+4*(lane>>5)
    const int co_b = 4 * lhi;
    if (!DW) {
        // bf16 NHWC output (+bias, +leaky)
        ushort_t* outb = (ushort_t*)outp + ((size_t)(b * 256 + h) * 256) * 64;
#pragma unroll
        for (int ct = 0; ct < 2; ++ct)
#pragma unroll
            for (int pt = 0; pt < 2; ++pt) {
                int pix = pw0 + pt * 32 + l31;
                ushort_t* po = outb + (size_t)pix * 64 + ct * 32 + co_b;
#pragma unroll
                for (int q = 0; q < 4; ++q) {
                    float4v bv = *(const float4v*)(bias + ct * 32 + co_b + 8 * q);
                    short4v sv;
#pragma unroll
                    for (int m = 0; m < 4; ++m) {
                        float v = acc[ct][pt][q * 4 + m] + bv[m];
                        if (LEAKY) v = lrelu(v);
                        sv[m] = (short)f2bf(v);
                    }
                    *(short4v*)(po + 8 * q) = sv;
                }
            }
    } else {
        // Fused final: out = dw(f2,kern)*mv + conv + bias, fp32 NCHW.
        float* po = (float*)outp;
        for (int ct = 0; ct < 2; ++ct) {
            __syncthreads();  // previous readers of xs done
            // stage f2: 3 rows x 258 pix x 32 co (this ct half), same swizzle
            for (int i = tid; i < 3 * 260 * 4; i += 256) {
                int g = i & 3;
                int p = (i >> 2) % 260;
                int r = (i >> 2) / 260;
                if (p >= 258) continue;
                int hs = h + r - 1, ws = p - 1;
                short8 v = (short8)0;
                if ((unsigned)hs < 256u && (unsigned)ws < 256u)
                    v = *(const short8*)(f2 + (((size_t)(b * 256 + hs) * 256 + ws) * 64 +
                                               ct * 32 + g * 8));
                int slot = ((p & 1) * 4 + g) ^ ((p >> 1) & 7);
                *(short8*)(xs + ((r * 130 + (p >> 1)) * 8 + slot) * 8) = v;
            }
            __syncthreads();

#pragma unroll
            for (int q = 0; q < 4; ++q) {
                // lane's 4 consecutive channels: co = ct*32 + 4*lhi + 8*q + m
                const int cb4 = ct * 32 + co_b + 8 * q;
                float4v kv[9];
#pragma unroll
                for (int t9 = 0; t9 < 9; ++t9)
                    kv[t9] = *(const float4v*)(ktr + b * 576 + t9 * 64 + cb4);
                float4v mvv = *(const float4v*)(mv + b * 64 + cb4);
                float4v bv = *(const float4v*)(bias + cb4);
#pragma unroll
                for (int pt = 0; pt < 2; ++pt) {
                    int pix = pw0 + pt * 32 + l31;
                    float dw4[4] = {0.f, 0.f, 0.f, 0.f};
#pragma unroll
                    for (int t9 = 0; t9 < 9; ++t9) {
                        int r = t9 / 3, dwx = t9 % 3;
                        int p = pix + dwx;
                        int slot = ((p & 1) * 4 + q) ^ ((p >> 1) & 7);
                        short4v sv = *(const short4v*)(
                            xs + ((r * 130 + (p >> 1)) * 8 + slot) * 8 + 4 * lhi);
#pragma unroll
                        for (int m = 0; m < 4; ++m)
                            dw4[m] = fmaf(kv[t9][m], bf2f((ushort_t)sv[m]), dw4[m]);
                    }
#pragma unroll
                    for (int m = 0; m < 4; ++m) {
                        float v = fmaf(dw4[m], mvv[m], acc[ct][pt][q * 4 + m] + bv[m]);
                        po[((size_t)(b * 64 + cb4 + m) << 16) + h * 256 + pix] = v;
                    }
                }
            }
        }
    }
}

// ---------------------------------------------------------------------------
extern "C" void kernel_launch(void* const* d_in, const int* in_sizes, int n_in,
                              void* d_out, int out_size, void* d_ws, size_t ws_size,
                              hipStream_t stream) {
    const float* x   = (const float*)d_in[0];
    const float* t   = (const float*)d_in[1];
    const float* tW1 = (const float*)d_in[2];
    const float* tW2 = (const float*)d_in[3];
    const float* fW1 = (const float*)d_in[4];
    const float* fb1 = (const float*)d_in[5];
    const float* fW2 = (const float*)d_in[6];
    const float* fb2 = (const float*)d_in[7];
    const float* kW1 = (const float*)d_in[8];
    const float* kW2 = (const float*)d_in[9];
    const float* cW  = (const float*)d_in[10];
    const float* cb  = (const float*)d_in[11];

    // ws: [mv 4KB][ktr 36KB][wpack @64KB, 216KB][xbf @1MB, 128MB][f2bf @129MB, 128MB]
    char* ws = (char*)d_ws;
    float*    mv    = (float*)ws;
    float*    ktr   = (float*)(ws + 4096);
    ushort_t* wp    = (ushort_t*)(ws + 65536);
    ushort_t* xbf   = (ushort_t*)(ws + (1u << 20));
    ushort_t* f2bf_ = (ushort_t*)(ws + (1u << 20) + ((size_t)128 << 20));
    ushort_t* f1bf  = (ushort_t*)d_out;  // first 128MB of d_out as scratch
    float*    out   = (float*)d_out;

    k_tiny<<<dim3(16), dim3(64), 0, stream>>>(t, tW1, tW2, kW1, kW2, mv, ktr);
    k_pack<<<dim3((3 * 36864 + 255) / 256), dim3(256), 0, stream>>>(fW1, fW2, cW, wp);
    k_tr<<<dim3(4096), dim3(256), 0, stream>>>(x, xbf);

    k_conv<true, false><<<dim3(4096), dim3(256), 0, stream>>>(
        xbf, wp, fb1, nullptr, nullptr, nullptr, (void*)f1bf);
    k_conv<true, false><<<dim3(4096), dim3(256), 0, stream>>>(
        f1bf, wp + 36864, fb2, nullptr, nullptr, nullptr, (void*)f2bf_);
    k_conv<false, true><<<dim3(4096), dim3(256), 0, stream>>>(
        xbf, wp + 2 * 36864, cb, f2bf_, ktr, mv, (void*)out);
}

// Round 4
// 842.157 us; speedup vs baseline: 1.1637x; 1.1637x over previous
//
#include <hip/hip_runtime.h>
#include <cstdint>

// B=16, C=64, H=W=256. Three 3x3 convs via bf16 MFMA implicit GEMM.
// Round 4: global_load_lds async staging (pre-swizzled source, linear LDS),
// bijective XCD swizzle for L2 row reuse, DW epilogue via direct global reads.
using short8  = __attribute__((ext_vector_type(8))) short;
using short4v = __attribute__((ext_vector_type(4))) short;
using f32x16  = __attribute__((ext_vector_type(16))) float;
using float4v = __attribute__((ext_vector_type(4))) float;
typedef unsigned short ushort_t;

__device__ __forceinline__ float lrelu(float x) { return x > 0.f ? x : 0.1f * x; }

__device__ __forceinline__ ushort_t f2bf(float f) {
    union { float f; unsigned u; } v; v.f = f;
    unsigned r = (v.u + 0x7FFFu + ((v.u >> 16) & 1u)) >> 16;
    return (ushort_t)r;
}
__device__ __forceinline__ float bf2f(ushort_t b) {
    union { unsigned u; float f; } v; v.u = ((unsigned)b) << 16; return v.f;
}

// async 16B global -> LDS (dest = wave-uniform base + lane*16)
__device__ __forceinline__ void gload_lds16(const ushort_t* g, ushort_t* l) {
    __builtin_amdgcn_global_load_lds(
        (const __attribute__((address_space(1))) void*)g,
        (__attribute__((address_space(3))) void*)l, 16, 0, 0);
}

// ---------------------------------------------------------------------------
// Tiny branch: mv[b][c]; kern transposed to ktr[b][tap][c].
// ---------------------------------------------------------------------------
__global__ void k_tiny(const float* __restrict__ t, const float* __restrict__ tW1,
                       const float* __restrict__ tW2, const float* __restrict__ kW1,
                       const float* __restrict__ kW2, float* __restrict__ mv,
                       float* __restrict__ ktr) {
    int b = blockIdx.x;
    int c = threadIdx.x;  // 64
    __shared__ float h1[64], g1[64];
    float ts = t[b];
    h1[c] = lrelu(ts * tW1[c]);
    g1[c] = lrelu(ts * kW1[c]);
    __syncthreads();
    float s = 0.f;
    for (int j = 0; j < 64; ++j) s = fmaf(tW2[c * 64 + j], h1[j], s);
    mv[b * 64 + c] = 1.f / (1.f + expf(-s));
    for (int q = 0; q < 9; ++q) {
        float s2 = 0.f;
        for (int j = 0; j < 64; ++j) s2 = fmaf(kW2[(c * 9 + q) * 64 + j], g1[j], s2);
        ktr[b * 576 + q * 64 + c] = lrelu(s2);
    }
}

// ---------------------------------------------------------------------------
// Zero row buffer (read for h out-of-range rows and w-edge source redirect).
// ---------------------------------------------------------------------------
__global__ void k_zrow(ushort_t* __restrict__ z) {
    int i = blockIdx.x * 256 + threadIdx.x;  // 2048 threads, 16384 shorts
    *(short8*)(z + (size_t)i * 8) = (short8)0;
}

// ---------------------------------------------------------------------------
// Pack three 64x64x3x3 weight tensors into MFMA A-fragment order (bf16).
// flat = (((t*2+ch)*2+kc)*2+ct)*512 + lane*8 + j
//   = W[co = ct*32 + (lane&31)][ci = ch*32 + kc*16 + (lane>>5)*8 + j], tap t
// ---------------------------------------------------------------------------
__global__ void k_pack(const float* __restrict__ w1, const float* __restrict__ w2,
                       const float* __restrict__ w3, ushort_t* __restrict__ wp) {
    int idx = blockIdx.x * 256 + threadIdx.x;
    if (idx >= 3 * 36864) return;
    int conv = idx / 36864, r = idx % 36864;
    const float* W = conv == 0 ? w1 : (conv == 1 ? w2 : w3);
    int j = r & 7, lane = (r >> 3) & 63, ct = (r >> 9) & 1, kc = (r >> 10) & 1,
        ch = (r >> 11) & 1, t = r >> 12;
    int co = ct * 32 + (lane & 31);
    int ci = ch * 32 + kc * 16 + (lane >> 5) * 8 + j;
    wp[idx] = f2bf(W[(co * 64 + ci) * 9 + t]);
}

// ---------------------------------------------------------------------------
// Transpose x: fp32 NCHW -> bf16 NHWC (width-256 rows). Block = (b,h).
// ---------------------------------------------------------------------------
__global__ __launch_bounds__(256) void k_tr(const float* __restrict__ x,
                                            ushort_t* __restrict__ xbf) {
    int bid = blockIdx.x;
    int h = bid & 255, b = bid >> 8;
    int t = threadIdx.x;
    for (int it = 0; it < 8; ++it) {
        int idx = t + it * 256;  // (w, g)
        int g = idx & 7, w = idx >> 3;
        const float* src = x + (((size_t)(b * 64 + g * 8) * 256 + h) * 256 + w);
        short8 v;
#pragma unroll
        for (int j = 0; j < 8; ++j) v[j] = (short)f2bf(src[(size_t)j * 65536]);
        *(short8*)(xbf + (((size_t)(b * 256 + h) * 256 + w) * 64 + g * 8)) = v;
    }
}

// ---------------------------------------------------------------------------
// 3x3 conv 64->64 via v_mfma_f32_32x32x16_bf16.
// Block = (b, h) after XCD swizzle: 4 waves, each 64 c_out x 64 pixels.
// LDS: 3136 slots x 16B = 50176 B (3 rows x 130 pixel-pairs x 8 slots + pad).
// Staging: global_load_lds, swizzle folded into per-lane source address:
//   slot S -> r=S/1040, m=(S%1040)>>3, sl=S&7; s'=sl^(m&7); p=2m+(s'>>2); g=s'&3
//   source = row[h+r-1][ws=p-1][ch*32+g*8] ; edges (ws<0|>255, bad h) -> zrow
// DW=true: epilogue computes dynamic depthwise from f2 via direct global
// reads (same-XCD L2 resident) + mv gate, writes fp32 NCHW.
// ---------------------------------------------------------------------------
template <bool LEAKY, bool DW>
__global__ __launch_bounds__(256, 3) void k_conv(const ushort_t* __restrict__ in,
                                                 const ushort_t* __restrict__ zv,
                                                 const ushort_t* __restrict__ wp,
                                                 const float* __restrict__ bias,
                                                 const ushort_t* __restrict__ f2,
                                                 const float* __restrict__ ktr,
                                                 const float* __restrict__ mv,
                                                 void* __restrict__ outp) {
    __shared__ __align__(16) ushort_t xs[3136 * 8];  // 50176 B
    const int tid = threadIdx.x;
    const int lane = tid & 63;
    const int wv = tid >> 6;
    const unsigned bid = blockIdx.x;
    const unsigned L = (bid & 7u) * 512u + (bid >> 3);  // XCD-contiguous h
    const int h = L & 255, b = L >> 8;
    const int l31 = lane & 31, lhi = lane >> 5;
    const int pw0 = wv * 64;

    const ushort_t* rb0 = (h > 0)   ? in + ((size_t)(b * 256 + h - 1)) * 16384 : zv;
    const ushort_t* rb1 =             in + ((size_t)(b * 256 + h)) * 16384;
    const ushort_t* rb2 = (h < 255) ? in + ((size_t)(b * 256 + h + 1)) * 16384 : zv;

    f32x16 acc[2][2];
#pragma unroll
    for (int a = 0; a < 2; ++a)
#pragma unroll
        for (int c = 0; c < 2; ++c) acc[a][c] = (f32x16)0.0f;

    for (int ch = 0; ch < 2; ++ch) {
        __syncthreads();  // previous-chunk readers done
#pragma unroll
        for (int it = 0; it < 13; ++it) {
            int base = it * 256 + wv * 64;  // wave-uniform
            if (base < 3120) {
                int S = base + lane;
                S = S < 3120 ? S : 3119;
                int r = (S >= 2080) ? 2 : (S >= 1040 ? 1 : 0);
                int rem = S - r * 1040;
                int m = rem >> 3, sl = rem & 7;
                int sp = sl ^ (m & 7);
                int p = 2 * m + (sp >> 2), g = sp & 3;
                int ws = p - 1;
                bool edge = (unsigned)ws >= 256u;
                const ushort_t* rp = (r == 0) ? rb0 : (r == 1 ? rb1 : rb2);
                const ushort_t* src =
                    edge ? zv : (rp + ws * 64 + ch * 32 + g * 8);
                gload_lds16(src, xs + (size_t)base * 8);
            }
        }
        asm volatile("s_waitcnt vmcnt(0)" ::: "memory");
        __syncthreads();

#pragma unroll
        for (int t = 0; t < 9; ++t) {
            const int dw = t % 3;
#pragma unroll
            for (int kc = 0; kc < 2; ++kc) {
                const ushort_t* wpf = wp + (((((t * 2 + ch) * 2 + kc) * 2) * 64 + lane) * 8);
                short8 a0 = *(const short8*)(wpf);
                short8 a1 = *(const short8*)(wpf + 512);
                const int g = kc * 2 + lhi;
                const int rr = t / 3;
#pragma unroll
                for (int pt = 0; pt < 2; ++pt) {
                    int p = pw0 + pt * 32 + l31 + dw;
                    int slot = ((p & 1) * 4 + g) ^ ((p >> 1) & 7);
                    short8 bf = *(const short8*)(xs + (((size_t)rr * 130 + (p >> 1)) * 8 + slot) * 8);
                    acc[0][pt] = __builtin_amdgcn_mfma_f32_32x32x16_bf16(a0, bf, acc[0][pt], 0, 0, 0);
                    acc[1][pt] = __builtin_amdgcn_mfma_f32_32x32x16_bf16(a1, bf, acc[1][pt], 0, 0, 0);
                }
            }
        }
    }

    // Epilogue. D layout: col(pix)=lane&31, row(co)=(reg&3)+8*(reg>>2)+4*(lane>>5)
    const int co_b = 4 * lhi;
    if (!DW) {
        ushort_t* outb = (ushort_t*)outp + ((size_t)(b * 256 + h)) * 16384;
#pragma unroll
        for (int ct = 0; ct < 2; ++ct)
#pragma unroll
            for (int pt = 0; pt < 2; ++pt) {
                int pix = pw0 + pt * 32 + l31;
                ushort_t* po = outb + (size_t)pix * 64 + ct * 32 + co_b;
#pragma unroll
                for (int q = 0; q < 4; ++q) {
                    float4v bv = *(const float4v*)(bias + ct * 32 + co_b + 8 * q);
                    short4v sv;
#pragma unroll
                    for (int m = 0; m < 4; ++m) {
                        float v = acc[ct][pt][q * 4 + m] + bv[m];
                        if (LEAKY) v = lrelu(v);
                        sv[m] = (short)f2bf(v);
                    }
                    *(short4v*)(po + 8 * q) = sv;
                }
            }
    } else {
        float* po = (float*)outp;
        const ushort_t* fr0 = (h > 0)   ? f2 + ((size_t)(b * 256 + h - 1)) * 16384 : zv;
        const ushort_t* fr1 =             f2 + ((size_t)(b * 256 + h)) * 16384;
        const ushort_t* fr2 = (h < 255) ? f2 + ((size_t)(b * 256 + h + 1)) * 16384 : zv;
#pragma unroll
        for (int ct = 0; ct < 2; ++ct)
#pragma unroll
            for (int q = 0; q < 4; ++q) {
                const int cb4 = ct * 32 + co_b + 8 * q;
                float4v kv[9];
#pragma unroll
                for (int t9 = 0; t9 < 9; ++t9)
                    kv[t9] = *(const float4v*)(ktr + b * 576 + t9 * 64 + cb4);
                float4v mvv = *(const float4v*)(mv + b * 64 + cb4);
                float4v bv = *(const float4v*)(bias + cb4);
#pragma unroll
                for (int pt = 0; pt < 2; ++pt) {
                    int pix = pw0 + pt * 32 + l31;
                    float dw4[4] = {0.f, 0.f, 0.f, 0.f};
#pragma unroll
                    for (int r = 0; r < 3; ++r) {
                        const ushort_t* fr = (r == 0) ? fr0 : (r == 1 ? fr1 : fr2);
#pragma unroll
                        for (int dx = 0; dx < 3; ++dx) {
                            int wsx = pix + dx - 1;
                            bool okx = (unsigned)wsx < 256u;
                            short4v sv = *(const short4v*)(fr + (size_t)(okx ? wsx : 0) * 64 + cb4);
                            if (!okx) sv = (short4v)0;
                            float4v kq = kv[r * 3 + dx];
#pragma unroll
                            for (int m = 0; m < 4; ++m)
                                dw4[m] = fmaf(kq[m], bf2f((ushort_t)sv[m]), dw4[m]);
                        }
                    }
#pragma unroll
                    for (int m = 0; m < 4; ++m) {
                        float v = fmaf(dw4[m], mvv[m], acc[ct][pt][q * 4 + m] + bv[m]);
                        po[((size_t)(b * 64 + cb4 + m) << 16) + h * 256 + pix] = v;
                    }
                }
            }
    }
}

// ---------------------------------------------------------------------------
extern "C" void kernel_launch(void* const* d_in, const int* in_sizes, int n_in,
                              void* d_out, int out_size, void* d_ws, size_t ws_size,
                              hipStream_t stream) {
    const float* x   = (const float*)d_in[0];
    const float* t   = (const float*)d_in[1];
    const float* tW1 = (const float*)d_in[2];
    const float* tW2 = (const float*)d_in[3];
    const float* fW1 = (const float*)d_in[4];
    const float* fb1 = (const float*)d_in[5];
    const float* fW2 = (const float*)d_in[6];
    const float* fb2 = (const float*)d_in[7];
    const float* kW1 = (const float*)d_in[8];
    const float* kW2 = (const float*)d_in[9];
    const float* cW  = (const float*)d_in[10];
    const float* cb  = (const float*)d_in[11];

    // ws: [mv 4K][ktr 36K @4096][wp 216K @65536][zv 32K @294912]
    //     [xbf 128MB @512K][f2bf 128MB @512K+128MB]  total ~256.5MB
    char* ws = (char*)d_ws;
    float*    mv    = (float*)ws;
    float*    ktr   = (float*)(ws + 4096);
    ushort_t* wp    = (ushort_t*)(ws + 65536);
    ushort_t* zv    = (ushort_t*)(ws + 294912);
    ushort_t* xbf   = (ushort_t*)(ws + (512u << 10));
    ushort_t* f2bf_ = (ushort_t*)(ws + (512u << 10) + ((size_t)128 << 20));
    ushort_t* f1bf  = (ushort_t*)d_out;  // scratch inside d_out
    float*    out   = (float*)d_out;

    k_tiny<<<dim3(16), dim3(64), 0, stream>>>(t, tW1, tW2, kW1, kW2, mv, ktr);
    k_zrow<<<dim3(8), dim3(256), 0, stream>>>(zv);
    k_pack<<<dim3((3 * 36864 + 255) / 256), dim3(256), 0, stream>>>(fW1, fW2, cW, wp);
    k_tr<<<dim3(4096), dim3(256), 0, stream>>>(x, xbf);

    k_conv<true, false><<<dim3(4096), dim3(256), 0, stream>>>(
        xbf, zv, wp, fb1, nullptr, nullptr, nullptr, (void*)f1bf);
    k_conv<true, false><<<dim3(4096), dim3(256), 0, stream>>>(
        f1bf, zv, wp + 36864, fb2, nullptr, nullptr, nullptr, (void*)f2bf_);
    k_conv<false, true><<<dim3(4096), dim3(256), 0, stream>>>(
        xbf, zv, wp + 2 * 36864, cb, f2bf_, ktr, mv, (void*)out);
}